// Round 9
// baseline (198.105 us; speedup 1.0000x reference)
//
#include <hip/hip_runtime.h>
#include <math.h>

#define D 128
#define BCAP 8192    // per-bucket col capacity
#define SLICE 64     // per-(partition-block, bucket) slot capacity
#define PB 256       // partition blocks

typedef __attribute__((ext_vector_type(8))) short bf16x8;
typedef __attribute__((ext_vector_type(4))) float f32x4;
typedef __attribute__((ext_vector_type(4))) unsigned int u32x4;

// ---- bf16 helpers (packed pair in a uint: low 16 = even channel) ----

__device__ inline float2 bf2f2(unsigned int u) {
    union { unsigned int i; float f; } a, b;
    a.i = u << 16;
    b.i = u & 0xffff0000u;
    return make_float2(a.f, b.f);
}

__device__ inline unsigned short f2bf(float f) {
    union { float f; unsigned int i; } u;
    u.f = f;
    unsigned int r = u.i + 0x7fffu + ((u.i >> 16) & 1u);  // RNE
    return (unsigned short)(r >> 16);
}

// fast ELU: x>0 ? x : exp(x)-1 via v_exp_f32 (~3 instrs vs ~30 for expm1f).
__device__ __forceinline__ float elu_fast(float r) {
    return r > 0.f ? r : __expf(r) - 1.f;
}

// ---------------- shared GEMM core (Ws already staged) ----------------
// Cb[N,128](bf16 packed) = A[N,128] @ W ; Ws bf16 [n][k] in LDS.
// 256 thr = 4 waves, 64 rows/block; wave: 16 rows x 128 cols, 4 k-steps.

__device__ __forceinline__ void gemm_core(unsigned short (*Ws)[136], int gbid,
                                          const void* __restrict__ Ain, int a_fp32,
                                          unsigned int* __restrict__ Cb, int N) {
    const int tid = threadIdx.x;
    const int wid = tid >> 6;
    const int lane = tid & 63;
    const int quad = lane >> 4;
    const int ln = lane & 15;
    const int m = gbid * 64 + wid * 16 + ln;
    const bool valid = (m < N);

    f32x4 acc[8];
#pragma unroll
    for (int c = 0; c < 8; ++c) acc[c] = (f32x4){0.f, 0.f, 0.f, 0.f};

    __syncthreads();

#pragma unroll
    for (int ks = 0; ks < 4; ++ks) {
        const int k0 = ks * 32;
        bf16x8 af;
        if (a_fp32) {
            const float* A = (const float*)Ain;
            float4 lo = make_float4(0.f, 0.f, 0.f, 0.f), hi = lo;
            if (valid) {
                lo = *(const float4*)&A[(size_t)m * 128 + k0 + quad * 8];
                hi = *(const float4*)&A[(size_t)m * 128 + k0 + quad * 8 + 4];
            }
            af[0] = (short)f2bf(lo.x); af[1] = (short)f2bf(lo.y);
            af[2] = (short)f2bf(lo.z); af[3] = (short)f2bf(lo.w);
            af[4] = (short)f2bf(hi.x); af[5] = (short)f2bf(hi.y);
            af[6] = (short)f2bf(hi.z); af[7] = (short)f2bf(hi.w);
        } else {
            const uint4* A4 = (const uint4*)Ain;
            uint4 v = valid ? A4[(size_t)m * 16 + ks * 4 + quad]
                            : make_uint4(0u, 0u, 0u, 0u);
            union { uint4 u; bf16x8 h; } cv;
            cv.u = v;
            af = cv.h;
        }
#pragma unroll
        for (int c = 0; c < 8; ++c) {
            bf16x8 bf = *(const bf16x8*)&Ws[c * 16 + ln][k0 + quad * 8];
            acc[c] = __builtin_amdgcn_mfma_f32_16x16x32_bf16(af, bf, acc[c], 0, 0, 0);
        }
    }

    const int rowbase = gbid * 64 + wid * 16 + quad * 4;
#pragma unroll
    for (int c = 0; c < 8; ++c) {
#pragma unroll
        for (int r = 0; r < 4; ++r) {
            float v = acc[c][r];
            float vn = __shfl_xor(v, 1);
            int grow = rowbase + r;
            if (!(ln & 1) && grow < N) {
                unsigned int u = (unsigned int)f2bf(v) | ((unsigned int)f2bf(vn) << 16);
                Cb[(size_t)grow * 64 + c * 8 + (ln >> 1)] = u;
            }
        }
    }
}

// ---------------- K1a: edge partition (LDS atomics) ----------------
// pairs is BUCKET-MAJOR: pairs[(bucket*256 + chunk)*SLICE + off] -> the
// reader (partB) sees a contiguous 64 KB window per bucket. Writers scatter
// either way (fire-and-forget); the reader's stalls are what matter.
// cellCnt likewise bucket-major: cellCnt[bucket*256 + chunk].

__global__ __launch_bounds__(256) void k1_part(
        const int* __restrict__ src, const int* __restrict__ dst,
        unsigned int* __restrict__ pairs, unsigned char* __restrict__ cellCnt,
        int e, int chunk) {
    __shared__ int cur[256];
    const int tid = threadIdx.x;
    const int bid = blockIdx.x;          // chunk id
    cur[tid] = 0;
    __syncthreads();
    const int e0 = bid * chunk;
    const int e1 = min(e0 + chunk, e);
    for (int i = e0 + tid; i < e1; i += 256) {
        int d = dst[i], s = src[i];
        int b = d >> 8;
        int off = atomicAdd(&cur[b], 1);
        if (off < SLICE)
            pairs[((size_t)(b * 256 + bid)) * SLICE + off] =
                (unsigned int)s | ((unsigned int)(d & 255) << 16);
    }
    __syncthreads();
    cellCnt[(size_t)tid * 256 + bid] = (unsigned char)min(cur[tid], SLICE);
}

// ---------------- K1b: gemm1 (x @ W1 -> hb1 bf16) || convW2 ----------------
// W1 staging fixed: 16 unrolled float4 loads per thread (was 64 serialized
// scalar loads ~200cy each, ~5us/block x 783 blocks of re-staging).

__global__ __launch_bounds__(256) void k1_gemm(
        const float* __restrict__ x, const float* __restrict__ W1,
        const float* __restrict__ W2, unsigned short* __restrict__ Wt2,
        unsigned int* __restrict__ hb1, int N, int gemmBlocks) {
    __shared__ __align__(16) unsigned short Ws[128][136];
    const int tid = threadIdx.x;
    const int bid = blockIdx.x;

    if (bid < gemmBlocks) {
#pragma unroll
        for (int j = 0; j < 16; ++j) {
            const int q = tid + j * 256;          // float4 index 0..4095
            const float4 w = ((const float4*)W1)[q];
            const int k = q >> 5;                 // W1 row (k index)
            const int n0 = (q & 31) * 4;          // W1 col (n index)
            Ws[n0 + 0][k] = f2bf(w.x);            // transposed LDS write
            Ws[n0 + 1][k] = f2bf(w.y);
            Ws[n0 + 2][k] = f2bf(w.z);
            Ws[n0 + 3][k] = f2bf(w.w);
        }
        gemm_core(Ws, bid, x, 1, hb1, N);         // syncthreads inside
    } else {
        int i = (bid - gemmBlocks) * 256 + tid;   // 0..16383
        int k = i >> 7, n = i & 127;
        Wt2[n * 128 + k] = f2bf(W2[i]);
    }
}

// ---------------- K2: per-bucket CSR build, contiguous-staged ----------------
// With bucket-major pairs, each block's stage is ONE contiguous 64 KB read:
// 4 rounds of fully-coalesced uint4 loads (4096 uint4 / 1024 thr). cellCnt
// read is a contiguous 256 B block. Count/scan/scatter run from LDS.

__global__ __launch_bounds__(1024) void partB(const unsigned int* __restrict__ pairs,
                                              const unsigned char* __restrict__ cellCnt,
                                              unsigned short* __restrict__ col,
                                              unsigned int* __restrict__ meta,
                                              float* __restrict__ dinv, int n) {
    __shared__ unsigned int cellS[256 * SLICE];   // 64 KB
    __shared__ int cnt[256];
    __shared__ int deg[256];
    __shared__ int sc[256];
    __shared__ int cur[256];
    const int b = blockIdx.x;
    const int tid = threadIdx.x;     // 0..1023
    const int ch = tid >> 2;         // chunk 0..255 (4 thr/cell)
    const int sub = tid & 3;

    {   // stage the bucket's contiguous 64 KB pairs window
        const uint4* gp = (const uint4*)(pairs + (size_t)b * (256 * SLICE));
        uint4* sp = (uint4*)cellS;
#pragma unroll
        for (int r = 0; r < 4; ++r) sp[tid + r * 1024] = gp[tid + r * 1024];
    }
    if (tid < 256) {
        cnt[tid] = min((int)cellCnt[(size_t)b * 256 + tid], SLICE);
        deg[tid] = 0;
    }
    __syncthreads();

    // count degrees from LDS
    const int c = cnt[ch];
    for (int q = sub; q < c; q += 4) atomicAdd(&deg[cellS[ch * SLICE + q] >> 16], 1);
    __syncthreads();

    // exclusive scan over 256 node-degrees
    if (tid < 256) sc[tid] = deg[tid];
    __syncthreads();
    for (int o = 1; o < 256; o <<= 1) {
        int t = 0;
        if (tid < 256 && tid >= o) t = sc[tid - o];
        __syncthreads();
        if (tid < 256) sc[tid] += t;
        __syncthreads();
    }
    if (tid < 256) {
        int v = deg[tid];
        int startw = sc[tid] - v;
        cur[tid] = startw;
        int node = b * 256 + tid;
        if (node < n) {
            meta[node] = ((unsigned int)(b * BCAP + startw) << 10) | (unsigned int)v;
            dinv[node] = rsqrtf((float)(v + 1));
        }
    }
    __syncthreads();

    // scatter from LDS into the bucket's CSR window
    for (int q = sub; q < c; q += 4) {
        unsigned int p = cellS[ch * SLICE + q];
        int dl = p >> 16;
        int off = atomicAdd(&cur[dl], 1);
        col[(size_t)b * BCAP + off] = (unsigned short)(p & 0xffffu);
    }
}

// ---------------- wave-wide agg body, reduce-scatter epilogue --------------
// One node per wave. Lane group g = lane>>4 handles neighbor i+4t+g; lane
// ln = lane&15 loads u32x4 = 8 channels. One gather instr = 4 full rows
// (1 KB); 4 gathers pinned co-live -> 16 rows per latency round.
// PRE=true: hb rows are pre-scaled by dinv (no per-neighbor dinv gathers).
// Butterfly reduce-SCATTER: each of 64 lanes ends owning 2 channels.

__device__ __forceinline__ void fma8(float w, u32x4 u, f32x4& a, f32x4& b) {
    float2 v0 = bf2f2(u.x), v1 = bf2f2(u.y), v2 = bf2f2(u.z), v3 = bf2f2(u.w);
    a[0] = fmaf(w, v0.x, a[0]); a[1] = fmaf(w, v0.y, a[1]);
    a[2] = fmaf(w, v1.x, a[2]); a[3] = fmaf(w, v1.y, a[3]);
    b[0] = fmaf(w, v2.x, b[0]); b[1] = fmaf(w, v2.y, b[1]);
    b[2] = fmaf(w, v3.x, b[2]); b[3] = fmaf(w, v3.y, b[3]);
}

__device__ __forceinline__ void add8(u32x4 u, f32x4& a, f32x4& b) {
    float2 v0 = bf2f2(u.x), v1 = bf2f2(u.y), v2 = bf2f2(u.z), v3 = bf2f2(u.w);
    a[0] += v0.x; a[1] += v0.y; a[2] += v1.x; a[3] += v1.y;
    b[0] += v2.x; b[1] += v2.y; b[2] += v3.x; b[3] += v3.y;
}

template <bool PRE>
__device__ __forceinline__ float2 agg_wave_rs(const unsigned int* __restrict__ hb,
                                              const unsigned short* __restrict__ col,
                                              const float* __restrict__ dinv,
                                              int node, int g, int ln,
                                              unsigned int m, float di) {
    const u32x4* hb4 = (const u32x4*)hb;   // row = 16 u32x4
    const int s0 = (int)(m >> 10);
    const int s1 = s0 + (int)(m & 1023u);

    f32x4 sA = (f32x4){0.f, 0.f, 0.f, 0.f};
    f32x4 sB = (f32x4){0.f, 0.f, 0.f, 0.f};
    {   // self term (group 0 only; PRE rows already carry their dinv)
        u32x4 su = hb4[((unsigned)node << 4) + ln];
        float ws = (g == 0) ? (PRE ? 1.f : di) : 0.f;
        fma8(ws, su, sA, sB);
    }

    int i = s0;
    for (; i + 16 <= s1; i += 16) {   // 16 neighbors per round
        const int c0 = col[i + g];
        const int c1 = col[i + 4 + g];
        const int c2 = col[i + 8 + g];
        const int c3 = col[i + 12 + g];
        float w0 = 0.f, w1 = 0.f, w2 = 0.f, w3 = 0.f;
        if (!PRE) { w0 = dinv[c0]; w1 = dinv[c1]; w2 = dinv[c2]; w3 = dinv[c3]; }
        u32x4 u0 = hb4[((unsigned)c0 << 4) + ln];
        u32x4 u1 = hb4[((unsigned)c1 << 4) + ln];
        u32x4 u2 = hb4[((unsigned)c2 << 4) + ln];
        u32x4 u3 = hb4[((unsigned)c3 << 4) + ln];
        asm volatile("" :: "v"(u0), "v"(u1), "v"(u2), "v"(u3));  // pin co-live
        if (PRE) {
            add8(u0, sA, sB); add8(u1, sA, sB);
            add8(u2, sA, sB); add8(u3, sA, sB);
        } else {
            fma8(w0, u0, sA, sB); fma8(w1, u1, sA, sB);
            fma8(w2, u2, sA, sB); fma8(w3, u3, sA, sB);
        }
    }
    while (i < s1) {                  // wave-uniform quad steps (<=3)
        const int t = i + g;
        const bool ok = (t < s1);
        const int cc = ok ? (int)col[t] : node;   // safe index
        u32x4 u = hb4[((unsigned)cc << 4) + ln];
        if (PRE) {
            if (ok) add8(u, sA, sB);
        } else {
            const float w = ok ? dinv[cc] : 0.f;
            fma8(w, u, sA, sB);
        }
        i += 4;
    }

    // reduce-scatter across the 4 groups
    f32x4 t;
#pragma unroll
    for (int k = 0; k < 4; ++k) {
        float pa = __shfl_xor(sA[k], 16);
        float pb = __shfl_xor(sB[k], 16);
        t[k] = (g & 1) ? (sB[k] + pb) : (sA[k] + pa);
    }
    float p0 = __shfl_xor(t[0], 32);
    float p1 = __shfl_xor(t[1], 32);
    float p2 = __shfl_xor(t[2], 32);
    float p3 = __shfl_xor(t[3], 32);
    float e0 = (g & 2) ? (t[2] + p2) : (t[0] + p0);
    float e1 = (g & 2) ? (t[3] + p3) : (t[1] + p1);
    return make_float2(e0, e1);   // channels ch0 = 8*ln+4*(g&1)+2*(g>>1), ch0+1
}

// ---------------- K3: agg1 + gemm2 fused, one node per wave ----------------
// Block = 1024 thr = 16 waves = 16 nodes (one MFMA row-tile). Full W2 staged
// once; waves 0..7 compute the 8 col-tiles of the 16x128 @ 128x128 product.
// GEMM epilogue pre-scales hb2 rows by dinv[row] so K4 needs no per-neighbor
// dinv gathers.

__global__ __launch_bounds__(1024, 4) void k3_agg_gemm(
        const unsigned int* __restrict__ hb1, const unsigned int* __restrict__ meta,
        const unsigned short* __restrict__ col, const float* __restrict__ dinv,
        const float* __restrict__ b1, const unsigned short* __restrict__ Wt2,
        unsigned int* __restrict__ hb2, int n) {
    __shared__ unsigned int g1s[16 * 68];                 // padded rows
    __shared__ __align__(16) unsigned short Ws[128][136]; // full W2 (bf16, [n][k])

    const int tid = threadIdx.x;
    const int wid = tid >> 6;        // 0..15 = node slot
    const int lane = tid & 63;
    const int g = lane >> 4;
    const int ln = lane & 15;
    const int nodeBase = blockIdx.x * 16;
    const int node = nodeBase + wid;

    // stage full W2: 1024 thr, 8 thr/row, 2x uint4 (16 shorts) each
    {
        const int nloc = tid >> 3;        // 0..127 (output col)
        const int kb = (tid & 7) * 16;    // shorts offset
        const uint4* gp = (const uint4*)(Wt2 + (size_t)nloc * 128 + kb);
        uint4* sp = (uint4*)&Ws[nloc][kb];
        sp[0] = gp[0];
        sp[1] = gp[1];
    }

    // aggregate this wave's node; lane owns channel-pair cp after scatter
    const int cp = 4 * ln + 2 * (g & 1) + (g >> 1);   // 0..63
    if (node < n) {
        const unsigned int m = meta[node];
        const float di = dinv[node];
        float2 e = agg_wave_rs<false>(hb1, col, dinv, node, g, ln, m, di);
        const float2 bv = ((const float2*)b1)[cp];
        float r0 = elu_fast(fmaf(di, e.x, bv.x));
        float r1 = elu_fast(fmaf(di, e.y, bv.y));
        g1s[wid * 68 + cp] = (unsigned int)f2bf(r0) | ((unsigned int)f2bf(r1) << 16);
    } else {
        g1s[wid * 68 + cp] = 0u;
    }
    __syncthreads();

    // GEMM: wave w (0..7) computes col-tile c = w (cols c*16 .. c*16+15)
    if (wid < 8) {
        const int quad = lane >> 4;
        f32x4 acc = (f32x4){0.f, 0.f, 0.f, 0.f};
#pragma unroll
        for (int ks = 0; ks < 4; ++ks) {
            bf16x8 af = *(const bf16x8*)&g1s[ln * 68 + ks * 16 + quad * 4];
            bf16x8 bf = *(const bf16x8*)&Ws[wid * 16 + ln][ks * 32 + quad * 8];
            acc = __builtin_amdgcn_mfma_f32_16x16x32_bf16(af, bf, acc, 0, 0, 0);
        }
#pragma unroll
        for (int r = 0; r < 4; ++r) {
            int grow = nodeBase + quad * 4 + r;
            float dsc = (grow < n) ? dinv[grow] : 0.f;   // pre-scale layer-2 rows
            float v = acc[r] * dsc;
            float vn = __shfl_xor(v, 1);
            if (!(ln & 1) && grow < n) {
                hb2[(size_t)grow * 64 + wid * 8 + (ln >> 1)] =
                    (unsigned int)f2bf(v) | ((unsigned int)f2bf(vn) << 16);
            }
        }
    }
}

// ---------------- K4: final aggregation + bias + ELU (fp32 out) -------------
// One node per wave; hb2 rows are pre-scaled -> no dinv gathers in the loop.

__global__ __launch_bounds__(256, 4) void agg_elu(const unsigned int* __restrict__ hb,
                                                  const unsigned int* __restrict__ meta,
                                                  const unsigned short* __restrict__ col,
                                                  const float* __restrict__ dinv,
                                                  const float* __restrict__ bias,
                                                  float* __restrict__ outf, int n) {
    const int wid = threadIdx.x >> 6;
    const int lane = threadIdx.x & 63;
    const int g = lane >> 4;
    const int ln = lane & 15;
    const int node = blockIdx.x * 4 + wid;
    if (node >= n) return;

    const unsigned int m = meta[node];
    const float di = dinv[node];
    float2 e = agg_wave_rs<true>(hb, col, dinv, node, g, ln, m, di);

    const int cp = 4 * ln + 2 * (g & 1) + (g >> 1);   // channel-pair 0..63
    const float2 bv = ((const float2*)bias)[cp];
    float2 r;
    r.x = elu_fast(fmaf(di, e.x, bv.x));
    r.y = elu_fast(fmaf(di, e.y, bv.y));
    ((float2*)outf)[(size_t)node * 64 + cp] = r;
}

// ---------------- launch ----------------

extern "C" void kernel_launch(void* const* d_in, const int* in_sizes, int n_in,
                              void* d_out, int out_size, void* d_ws, size_t ws_size,
                              hipStream_t stream) {
    const float* x  = (const float*)d_in[0];
    const int*   ei = (const int*)d_in[1];
    const float* W1 = (const float*)d_in[2];
    const float* b1 = (const float*)d_in[3];
    const float* W2 = (const float*)d_in[4];
    const float* b2 = (const float*)d_in[5];
    float* out = (float*)d_out;

    const int N = in_sizes[0] / D;   // 50000 < 65536 -> u16 col ids valid
    const int E = in_sizes[1] / 2;
    const int* src = ei;
    const int* dst = ei + E;
    const int NB = (N + 255) / 256;  // buckets

    char* ws = (char*)d_ws;
    size_t off = 0;
    auto alloc = [&](size_t bytes) -> void* {
        void* p = ws + off;
        off = (off + bytes + 255) & ~(size_t)255;
        return p;
    };
    unsigned int*   pairs   = (unsigned int*)alloc((size_t)256 * PB * SLICE * 4);  // bucket-major
    unsigned char*  cellCnt = (unsigned char*)alloc((size_t)256 * PB);             // bucket-major
    unsigned short* col     = (unsigned short*)alloc((size_t)NB * BCAP * 2);
    unsigned int*   meta    = (unsigned int*)alloc((size_t)N * 4);
    float*          dinv    = (float*)alloc((size_t)N * 4);
    unsigned short* Wt2     = (unsigned short*)alloc(128 * 128 * 2);
    unsigned int*   hb1     = (unsigned int*)alloc((size_t)N * 64 * 4);  // layer-1 gemm out (bf16)
    unsigned int*   hb2     = (unsigned int*)alloc((size_t)N * 64 * 4);  // layer-2 gemm out (bf16, dinv-prescaled)
    (void)ws_size; (void)n_in; (void)out_size;

    const int chunk = (E + PB - 1) / PB;
    const int gemmBlocks = (N + 63) / 64;

    // K1a: edge partition (LDS atomics, bucket-major pairs)
    k1_part<<<PB, 256, 0, stream>>>(src, dst, pairs, cellCnt, E, chunk);
    // K1b: hb1 = bf16(x @ W1) || Wt2 = bf16(W2^T)
    k1_gemm<<<gemmBlocks + 64, 256, 0, stream>>>(x, W1, W2, Wt2, hb1, N, gemmBlocks);
    // K2: CSR build (col, meta, dinv) — contiguous 64 KB stage per bucket
    partB<<<NB, 1024, 0, stream>>>(pairs, cellCnt, col, meta, dinv, N);
    // K3: hb2 = bf16( dinv * (ELU(Agg(hb1)+b1) @ W2) )  [1 node/wave]
    k3_agg_gemm<<<(N + 15) / 16, 1024, 0, stream>>>(hb1, meta, col, dinv, b1, Wt2, hb2, N);
    // K4: out = ELU(Agg(hb2) + b2)   [fp32, prescaled rows -> no dinv gathers]
    agg_elu<<<(N + 3) / 4, 256, 0, stream>>>(hb2, meta, col, dinv, b2, out, N);
}

// Round 11
// 192.451 us; speedup vs baseline: 1.0294x; 1.0294x over previous
//
#include <hip/hip_runtime.h>
#include <math.h>

#define D 128
#define BCAP 8192    // per-bucket col capacity
#define SLICE 64     // per-(partition-block, bucket) slot capacity
#define PB 256       // partition blocks

typedef __attribute__((ext_vector_type(8))) short bf16x8;
typedef __attribute__((ext_vector_type(4))) float f32x4;
typedef __attribute__((ext_vector_type(4))) unsigned int u32x4;

// ---- bf16 helpers (packed pair in a uint: low 16 = even channel) ----

__device__ inline float2 bf2f2(unsigned int u) {
    union { unsigned int i; float f; } a, b;
    a.i = u << 16;
    b.i = u & 0xffff0000u;
    return make_float2(a.f, b.f);
}

__device__ inline unsigned short f2bf(float f) {
    union { float f; unsigned int i; } u;
    u.f = f;
    unsigned int r = u.i + 0x7fffu + ((u.i >> 16) & 1u);  // RNE
    return (unsigned short)(r >> 16);
}

// fast ELU: x>0 ? x : exp(x)-1 via v_exp_f32.
__device__ __forceinline__ float elu_fast(float r) {
    return r > 0.f ? r : __expf(r) - 1.f;
}

// ---------------- shared GEMM core (Ws already staged) ----------------
// Cb[N,128](bf16 packed) = A[N,128] @ W ; Ws bf16 [n][k] in LDS.
// 256 thr = 4 waves, 64 rows/block; wave: 16 rows x 128 cols, 4 k-steps.

__device__ __forceinline__ void gemm_core(unsigned short (*Ws)[136], int gbid,
                                          const void* __restrict__ Ain, int a_fp32,
                                          unsigned int* __restrict__ Cb, int N) {
    const int tid = threadIdx.x;
    const int wid = tid >> 6;
    const int lane = tid & 63;
    const int quad = lane >> 4;
    const int ln = lane & 15;
    const int m = gbid * 64 + wid * 16 + ln;
    const bool valid = (m < N);

    f32x4 acc[8];
#pragma unroll
    for (int c = 0; c < 8; ++c) acc[c] = (f32x4){0.f, 0.f, 0.f, 0.f};

    __syncthreads();

#pragma unroll
    for (int ks = 0; ks < 4; ++ks) {
        const int k0 = ks * 32;
        bf16x8 af;
        if (a_fp32) {
            const float* A = (const float*)Ain;
            float4 lo = make_float4(0.f, 0.f, 0.f, 0.f), hi = lo;
            if (valid) {
                lo = *(const float4*)&A[(size_t)m * 128 + k0 + quad * 8];
                hi = *(const float4*)&A[(size_t)m * 128 + k0 + quad * 8 + 4];
            }
            af[0] = (short)f2bf(lo.x); af[1] = (short)f2bf(lo.y);
            af[2] = (short)f2bf(lo.z); af[3] = (short)f2bf(lo.w);
            af[4] = (short)f2bf(hi.x); af[5] = (short)f2bf(hi.y);
            af[6] = (short)f2bf(hi.z); af[7] = (short)f2bf(hi.w);
        } else {
            const uint4* A4 = (const uint4*)Ain;
            uint4 v = valid ? A4[(size_t)m * 16 + ks * 4 + quad]
                            : make_uint4(0u, 0u, 0u, 0u);
            union { uint4 u; bf16x8 h; } cv;
            cv.u = v;
            af = cv.h;
        }
#pragma unroll
        for (int c = 0; c < 8; ++c) {
            bf16x8 bf = *(const bf16x8*)&Ws[c * 16 + ln][k0 + quad * 8];
            acc[c] = __builtin_amdgcn_mfma_f32_16x16x32_bf16(af, bf, acc[c], 0, 0, 0);
        }
    }

    const int rowbase = gbid * 64 + wid * 16 + quad * 4;
#pragma unroll
    for (int c = 0; c < 8; ++c) {
#pragma unroll
        for (int r = 0; r < 4; ++r) {
            float v = acc[c][r];
            float vn = __shfl_xor(v, 1);
            int grow = rowbase + r;
            if (!(ln & 1) && grow < N) {
                unsigned int u = (unsigned int)f2bf(v) | ((unsigned int)f2bf(vn) << 16);
                Cb[(size_t)grow * 64 + c * 8 + (ln >> 1)] = u;
            }
        }
    }
}

// ---------------- K1: partition || gemm1 || convW2 (fused, bucket-major) ----

__global__ __launch_bounds__(256) void k1_all(
        const int* __restrict__ src, const int* __restrict__ dst,
        const float* __restrict__ x, const float* __restrict__ W1,
        const float* __restrict__ W2, unsigned short* __restrict__ Wt2,
        unsigned int* __restrict__ pairs, unsigned char* __restrict__ cellCnt,
        unsigned int* __restrict__ hb1, int e, int chunk, int N, int gemmBlocks) {
    __shared__ __align__(16) unsigned char smem[128 * 136 * 2];
    const int tid = threadIdx.x;
    const int bid = blockIdx.x;

    if (bid < PB) {
        int* cur = (int*)smem;
        cur[tid] = 0;
        __syncthreads();
        const int e0 = bid * chunk;
        const int e1 = min(e0 + chunk, e);
        for (int i = e0 + tid; i < e1; i += 256) {
            int d = dst[i], s = src[i];
            int b = d >> 8;
            int off = atomicAdd(&cur[b], 1);
            if (off < SLICE)
                pairs[((size_t)(b * 256 + bid)) * SLICE + off] =
                    (unsigned int)s | ((unsigned int)(d & 255) << 16);
        }
        __syncthreads();
        cellCnt[(size_t)tid * 256 + bid] = (unsigned char)min(cur[tid], SLICE);
    } else if (bid < PB + gemmBlocks) {
        unsigned short (*Ws)[136] = (unsigned short(*)[136])smem;
#pragma unroll
        for (int j = 0; j < 16; ++j) {
            const int q = tid + j * 256;          // float4 index 0..4095
            const float4 w = ((const float4*)W1)[q];
            const int k = q >> 5;                 // W1 row (k index)
            const int n0 = (q & 31) * 4;          // W1 col (n index)
            Ws[n0 + 0][k] = f2bf(w.x);            // transposed LDS write
            Ws[n0 + 1][k] = f2bf(w.y);
            Ws[n0 + 2][k] = f2bf(w.z);
            Ws[n0 + 3][k] = f2bf(w.w);
        }
        gemm_core(Ws, bid - PB, x, 1, hb1, N);    // syncthreads inside
    } else {
        int i = (bid - PB - gemmBlocks) * 256 + tid; // 0..16383
        int k = i >> 7, n = i & 127;
        Wt2[n * 128 + k] = f2bf(W2[i]);
    }
}

// ---------------- K2: per-bucket CSR build, contiguous-staged ---------------

__global__ __launch_bounds__(1024) void partB(const unsigned int* __restrict__ pairs,
                                              const unsigned char* __restrict__ cellCnt,
                                              unsigned short* __restrict__ col,
                                              unsigned int* __restrict__ meta,
                                              float* __restrict__ dinv, int n) {
    __shared__ unsigned int cellS[256 * SLICE];   // 64 KB
    __shared__ int cnt[256];
    __shared__ int deg[256];
    __shared__ int sc[256];
    __shared__ int cur[256];
    const int b = blockIdx.x;
    const int tid = threadIdx.x;     // 0..1023
    const int ch = tid >> 2;         // chunk 0..255 (4 thr/cell)
    const int sub = tid & 3;

    {   // stage the bucket's contiguous 64 KB pairs window
        const uint4* gp = (const uint4*)(pairs + (size_t)b * (256 * SLICE));
        uint4* sp = (uint4*)cellS;
#pragma unroll
        for (int r = 0; r < 4; ++r) sp[tid + r * 1024] = gp[tid + r * 1024];
    }
    if (tid < 256) {
        cnt[tid] = min((int)cellCnt[(size_t)b * 256 + tid], SLICE);
        deg[tid] = 0;
    }
    __syncthreads();

    const int c = cnt[ch];
    for (int q = sub; q < c; q += 4) atomicAdd(&deg[cellS[ch * SLICE + q] >> 16], 1);
    __syncthreads();

    if (tid < 256) sc[tid] = deg[tid];
    __syncthreads();
    for (int o = 1; o < 256; o <<= 1) {
        int t = 0;
        if (tid < 256 && tid >= o) t = sc[tid - o];
        __syncthreads();
        if (tid < 256) sc[tid] += t;
        __syncthreads();
    }
    if (tid < 256) {
        int v = deg[tid];
        int startw = sc[tid] - v;
        cur[tid] = startw;
        int node = b * 256 + tid;
        if (node < n) {
            meta[node] = ((unsigned int)(b * BCAP + startw) << 10) | (unsigned int)v;
            dinv[node] = rsqrtf((float)(v + 1));
        }
    }
    __syncthreads();

    for (int q = sub; q < c; q += 4) {
        unsigned int p = cellS[ch * SLICE + q];
        int dl = p >> 16;
        int off = atomicAdd(&cur[dl], 1);
        col[(size_t)b * BCAP + off] = (unsigned short)(p & 0xffffu);
    }
}

// ---------------- wave-wide agg body: FLAT-TAIL, reduce-scatter -------------
// One node per wave. Lane group g = lane>>4, lane ln = lane&15 holds a
// u32x4 = 8 channels. Old tail: up to 4 SERIAL 4-neighbor rounds (~500cy
// each) — the longest pole at deg~17. New: the final <32 neighbors are 8
// PREDICATED quads with ALL row loads issued in ONE round (indices clamped
// to the node's own L1-hot row, weights zeroed); one keepalive pins the 9
// row vectors co-live. Per node: col round -> row round -> compute.

__device__ __forceinline__ void fma8(float w, u32x4 u, f32x4& a, f32x4& b) {
    float2 v0 = bf2f2(u.x), v1 = bf2f2(u.y), v2 = bf2f2(u.z), v3 = bf2f2(u.w);
    a[0] = fmaf(w, v0.x, a[0]); a[1] = fmaf(w, v0.y, a[1]);
    a[2] = fmaf(w, v1.x, a[2]); a[3] = fmaf(w, v1.y, a[3]);
    b[0] = fmaf(w, v2.x, b[0]); b[1] = fmaf(w, v2.y, b[1]);
    b[2] = fmaf(w, v3.x, b[2]); b[3] = fmaf(w, v3.y, b[3]);
}

template <bool PRE>
__device__ __forceinline__ float2 agg_wave_rs(const unsigned int* __restrict__ hb,
                                              const unsigned short* __restrict__ col,
                                              const float* __restrict__ dinv,
                                              int node, int g, int ln,
                                              unsigned int m, float di) {
    const u32x4* hb4 = (const u32x4*)hb;   // row = 16 u32x4
    const int s0 = (int)(m >> 10);
    const int s1 = s0 + (int)(m & 1023u);

    f32x4 sA = (f32x4){0.f, 0.f, 0.f, 0.f};
    f32x4 sB = (f32x4){0.f, 0.f, 0.f, 0.f};

    // self row: issue early (consumed in the flat finale)
    u32x4 su = hb4[((unsigned)node << 4) + ln];

    int i = s0;
    // deep-degree loop (deg >= 32; ~0.02% of nodes at Poisson(16))
    while (i + 32 <= s1) {
        const int c0 = col[i + g];
        const int c1 = col[i + 4 + g];
        const int c2 = col[i + 8 + g];
        const int c3 = col[i + 12 + g];
        float w0 = 1.f, w1 = 1.f, w2 = 1.f, w3 = 1.f;
        if (!PRE) { w0 = dinv[c0]; w1 = dinv[c1]; w2 = dinv[c2]; w3 = dinv[c3]; }
        u32x4 u0 = hb4[((unsigned)c0 << 4) + ln];
        u32x4 u1 = hb4[((unsigned)c1 << 4) + ln];
        u32x4 u2 = hb4[((unsigned)c2 << 4) + ln];
        u32x4 u3 = hb4[((unsigned)c3 << 4) + ln];
        asm volatile("" :: "v"(u0), "v"(u1), "v"(u2), "v"(u3));
        fma8(w0, u0, sA, sB); fma8(w1, u1, sA, sB);
        fma8(w2, u2, sA, sB); fma8(w3, u3, sA, sB);
        i += 16;
    }

    {   // flat finale: rem in [0,32) as 8 predicated quads, one load round.
        const int t0 = i + g,       t1 = i + 4 + g;
        const int t2 = i + 8 + g,   t3 = i + 12 + g;
        const int t4 = i + 16 + g,  t5 = i + 20 + g;
        const int t6 = i + 24 + g,  t7 = i + 28 + g;
        const int c0 = (t0 < s1) ? (int)col[t0] : node;
        const int c1 = (t1 < s1) ? (int)col[t1] : node;
        const int c2 = (t2 < s1) ? (int)col[t2] : node;
        const int c3 = (t3 < s1) ? (int)col[t3] : node;
        const int c4 = (t4 < s1) ? (int)col[t4] : node;
        const int c5 = (t5 < s1) ? (int)col[t5] : node;
        const int c6 = (t6 < s1) ? (int)col[t6] : node;
        const int c7 = (t7 < s1) ? (int)col[t7] : node;
        const float w0 = (t0 < s1) ? (PRE ? 1.f : dinv[c0]) : 0.f;
        const float w1 = (t1 < s1) ? (PRE ? 1.f : dinv[c1]) : 0.f;
        const float w2 = (t2 < s1) ? (PRE ? 1.f : dinv[c2]) : 0.f;
        const float w3 = (t3 < s1) ? (PRE ? 1.f : dinv[c3]) : 0.f;
        const float w4 = (t4 < s1) ? (PRE ? 1.f : dinv[c4]) : 0.f;
        const float w5 = (t5 < s1) ? (PRE ? 1.f : dinv[c5]) : 0.f;
        const float w6 = (t6 < s1) ? (PRE ? 1.f : dinv[c6]) : 0.f;
        const float w7 = (t7 < s1) ? (PRE ? 1.f : dinv[c7]) : 0.f;
        u32x4 u0 = hb4[((unsigned)c0 << 4) + ln];
        u32x4 u1 = hb4[((unsigned)c1 << 4) + ln];
        u32x4 u2 = hb4[((unsigned)c2 << 4) + ln];
        u32x4 u3 = hb4[((unsigned)c3 << 4) + ln];
        u32x4 u4 = hb4[((unsigned)c4 << 4) + ln];
        u32x4 u5 = hb4[((unsigned)c5 << 4) + ln];
        u32x4 u6 = hb4[((unsigned)c6 << 4) + ln];
        u32x4 u7 = hb4[((unsigned)c7 << 4) + ln];
        asm volatile("" :: "v"(u0), "v"(u1), "v"(u2), "v"(u3),
                          "v"(u4), "v"(u5), "v"(u6), "v"(u7), "v"(su));
        const float ws = (g == 0) ? (PRE ? 1.f : di) : 0.f;   // self term
        fma8(ws, su, sA, sB);
        fma8(w0, u0, sA, sB); fma8(w1, u1, sA, sB);
        fma8(w2, u2, sA, sB); fma8(w3, u3, sA, sB);
        fma8(w4, u4, sA, sB); fma8(w5, u5, sA, sB);
        fma8(w6, u6, sA, sB); fma8(w7, u7, sA, sB);
    }

    // reduce-scatter across the 4 groups
    f32x4 t;
#pragma unroll
    for (int k = 0; k < 4; ++k) {
        float pa = __shfl_xor(sA[k], 16);
        float pb = __shfl_xor(sB[k], 16);
        t[k] = (g & 1) ? (sB[k] + pb) : (sA[k] + pa);
    }
    float p0 = __shfl_xor(t[0], 32);
    float p1 = __shfl_xor(t[1], 32);
    float p2 = __shfl_xor(t[2], 32);
    float p3 = __shfl_xor(t[3], 32);
    float e0 = (g & 2) ? (t[2] + p2) : (t[0] + p0);
    float e1 = (g & 2) ? (t[3] + p3) : (t[1] + p1);
    return make_float2(e0, e1);   // channels ch0 = 8*ln+4*(g&1)+2*(g>>1), ch0+1
}

// ---------------- K3: agg1 + gemm2 fused, one node per wave ----------------

__global__ __launch_bounds__(1024, 4) void k3_agg_gemm(
        const unsigned int* __restrict__ hb1, const unsigned int* __restrict__ meta,
        const unsigned short* __restrict__ col, const float* __restrict__ dinv,
        const float* __restrict__ b1, const unsigned short* __restrict__ Wt2,
        unsigned int* __restrict__ hb2, int n) {
    __shared__ unsigned int g1s[16 * 68];                 // padded rows
    __shared__ __align__(16) unsigned short Ws[128][136]; // full W2 (bf16, [n][k])

    const int tid = threadIdx.x;
    const int wid = tid >> 6;        // 0..15 = node slot
    const int lane = tid & 63;
    const int g = lane >> 4;
    const int ln = lane & 15;
    const int nodeBase = blockIdx.x * 16;
    const int node = nodeBase + wid;

    // stage full W2: 1024 thr, 8 thr/row, 2x uint4 (16 shorts) each
    {
        const int nloc = tid >> 3;        // 0..127 (output col)
        const int kb = (tid & 7) * 16;    // shorts offset
        const uint4* gp = (const uint4*)(Wt2 + (size_t)nloc * 128 + kb);
        uint4* sp = (uint4*)&Ws[nloc][kb];
        sp[0] = gp[0];
        sp[1] = gp[1];
    }

    // aggregate this wave's node; lane owns channel-pair cp after scatter
    const int cp = 4 * ln + 2 * (g & 1) + (g >> 1);   // 0..63
    if (node < n) {
        const unsigned int m = meta[node];
        const float di = dinv[node];
        float2 e = agg_wave_rs<false>(hb1, col, dinv, node, g, ln, m, di);
        const float2 bv = ((const float2*)b1)[cp];
        float r0 = elu_fast(fmaf(di, e.x, bv.x));
        float r1 = elu_fast(fmaf(di, e.y, bv.y));
        g1s[wid * 68 + cp] = (unsigned int)f2bf(r0) | ((unsigned int)f2bf(r1) << 16);
    } else {
        g1s[wid * 68 + cp] = 0u;
    }
    __syncthreads();

    // GEMM: wave w (0..7) computes col-tile c = w (cols c*16 .. c*16+15)
    if (wid < 8) {
        const int quad = lane >> 4;
        f32x4 acc = (f32x4){0.f, 0.f, 0.f, 0.f};
#pragma unroll
        for (int ks = 0; ks < 4; ++ks) {
            bf16x8 af = *(const bf16x8*)&g1s[ln * 68 + ks * 16 + quad * 4];
            bf16x8 bf = *(const bf16x8*)&Ws[wid * 16 + ln][ks * 32 + quad * 8];
            acc = __builtin_amdgcn_mfma_f32_16x16x32_bf16(af, bf, acc, 0, 0, 0);
        }
#pragma unroll
        for (int r = 0; r < 4; ++r) {
            int grow = nodeBase + quad * 4 + r;
            float dsc = (grow < n) ? dinv[grow] : 0.f;   // pre-scale layer-2 rows
            float v = acc[r] * dsc;
            float vn = __shfl_xor(v, 1);
            if (!(ln & 1) && grow < n) {
                hb2[(size_t)grow * 64 + wid * 8 + (ln >> 1)] =
                    (unsigned int)f2bf(v) | ((unsigned int)f2bf(vn) << 16);
            }
        }
    }
}

// ---------------- K4: final aggregation + bias + ELU (fp32 out) -------------

__global__ __launch_bounds__(256, 4) void agg_elu(const unsigned int* __restrict__ hb,
                                                  const unsigned int* __restrict__ meta,
                                                  const unsigned short* __restrict__ col,
                                                  const float* __restrict__ dinv,
                                                  const float* __restrict__ bias,
                                                  float* __restrict__ outf, int n) {
    const int wid = threadIdx.x >> 6;
    const int lane = threadIdx.x & 63;
    const int g = lane >> 4;
    const int ln = lane & 15;
    const int node = blockIdx.x * 4 + wid;
    if (node >= n) return;

    const unsigned int m = meta[node];
    const float di = dinv[node];
    float2 e = agg_wave_rs<true>(hb, col, dinv, node, g, ln, m, di);

    const int cp = 4 * ln + 2 * (g & 1) + (g >> 1);   // channel-pair 0..63
    const float2 bv = ((const float2*)bias)[cp];
    float2 r;
    r.x = elu_fast(fmaf(di, e.x, bv.x));
    r.y = elu_fast(fmaf(di, e.y, bv.y));
    ((float2*)outf)[(size_t)node * 64 + cp] = r;
}

// ---------------- launch ----------------

extern "C" void kernel_launch(void* const* d_in, const int* in_sizes, int n_in,
                              void* d_out, int out_size, void* d_ws, size_t ws_size,
                              hipStream_t stream) {
    const float* x  = (const float*)d_in[0];
    const int*   ei = (const int*)d_in[1];
    const float* W1 = (const float*)d_in[2];
    const float* b1 = (const float*)d_in[3];
    const float* W2 = (const float*)d_in[4];
    const float* b2 = (const float*)d_in[5];
    float* out = (float*)d_out;

    const int N = in_sizes[0] / D;   // 50000 < 65536 -> u16 col ids valid
    const int E = in_sizes[1] / 2;
    const int* src = ei;
    const int* dst = ei + E;
    const int NB = (N + 255) / 256;  // buckets

    char* ws = (char*)d_ws;
    size_t off = 0;
    auto alloc = [&](size_t bytes) -> void* {
        void* p = ws + off;
        off = (off + bytes + 255) & ~(size_t)255;
        return p;
    };
    unsigned int*   pairs   = (unsigned int*)alloc((size_t)256 * PB * SLICE * 4);  // bucket-major
    unsigned char*  cellCnt = (unsigned char*)alloc((size_t)256 * PB);             // bucket-major
    unsigned short* col     = (unsigned short*)alloc((size_t)NB * BCAP * 2);
    unsigned int*   meta    = (unsigned int*)alloc((size_t)N * 4);
    float*          dinv    = (float*)alloc((size_t)N * 4);
    unsigned short* Wt2     = (unsigned short*)alloc(128 * 128 * 2);
    unsigned int*   hb1     = (unsigned int*)alloc((size_t)N * 64 * 4);  // layer-1 gemm out (bf16)
    unsigned int*   hb2     = (unsigned int*)alloc((size_t)N * 64 * 4);  // layer-2 gemm out (bf16, dinv-prescaled)
    (void)ws_size; (void)n_in; (void)out_size;

    const int chunk = (E + PB - 1) / PB;
    const int gemmBlocks = (N + 63) / 64;

    // K1: edge partition || hb1 = bf16(x @ W1) || Wt2 = bf16(W2^T)
    k1_all<<<PB + gemmBlocks + 64, 256, 0, stream>>>(src, dst, x, W1, W2, Wt2,
                                                     pairs, cellCnt, hb1, E, chunk,
                                                     N, gemmBlocks);
    // K2: CSR build (col, meta, dinv) — contiguous 64 KB stage per bucket
    partB<<<NB, 1024, 0, stream>>>(pairs, cellCnt, col, meta, dinv, N);
    // K3: hb2 = bf16( dinv * (ELU(Agg(hb1)+b1) @ W2) )  [1 node/wave, flat tail]
    k3_agg_gemm<<<(N + 15) / 16, 1024, 0, stream>>>(hb1, meta, col, dinv, b1, Wt2, hb2, N);
    // K4: out = ELU(Agg(hb2) + b2)   [fp32, flat tail]
    agg_elu<<<(N + 3) / 4, 256, 0, stream>>>(hb2, meta, col, dinv, b2, out, N);
}